// Round 1
// baseline (81.832 us; speedup 1.0000x reference)
//
#include <hip/hip_runtime.h>

// AbstractRelu (DeepPoly ReLU relaxation), elementwise over N=16M fp32.
// Outputs concatenated: [x_out | low_out | high_out], each N floats.
// Memory-bound: 192 MiB in + 192 MiB out. float4 vectorization, grid-stride.

#define EPS 1e-7f

__device__ __forceinline__ void relax_one(float X, float L, float H,
                                          float& xo, float& lo, float& ho) {
    xo = fmaxf(X, 0.0f);

    const bool crossing = (L < 0.0f) & (H > 0.0f);
    const bool dead = (H <= 0.0f);

    // Match reference exactly: denom = crossing ? (H-L) : 1.0
    // ub_slope uses denom+EPS, ub_int uses bare denom.
    const float denom = crossing ? (H - L) : 1.0f;
    const float ub_slope = H / (denom + EPS);
    const float ub_int = -(L * H) / denom;
    const float high_cross = ub_slope * H + ub_int;
    // LAMDA = 0 -> low_cross = 0

    ho = crossing ? high_cross : (dead ? 0.0f : H);
    lo = crossing ? 0.0f : (dead ? 0.0f : L);
}

__global__ void __launch_bounds__(256)
abstract_relu_kernel(const float4* __restrict__ x,
                     const float4* __restrict__ low,
                     const float4* __restrict__ high,
                     float4* __restrict__ x_out,
                     float4* __restrict__ low_out,
                     float4* __restrict__ high_out,
                     int n4) {
    const int stride = gridDim.x * blockDim.x;
    for (int i = blockIdx.x * blockDim.x + threadIdx.x; i < n4; i += stride) {
        const float4 xv = x[i];
        const float4 lv = low[i];
        const float4 hv = high[i];
        float4 xr, lr, hr;
        relax_one(xv.x, lv.x, hv.x, xr.x, lr.x, hr.x);
        relax_one(xv.y, lv.y, hv.y, xr.y, lr.y, hr.y);
        relax_one(xv.z, lv.z, hv.z, xr.z, lr.z, hr.z);
        relax_one(xv.w, lv.w, hv.w, xr.w, lr.w, hr.w);
        x_out[i] = xr;
        low_out[i] = lr;
        high_out[i] = hr;
    }
}

extern "C" void kernel_launch(void* const* d_in, const int* in_sizes, int n_in,
                              void* d_out, int out_size, void* d_ws, size_t ws_size,
                              hipStream_t stream) {
    const int n = in_sizes[0];          // 16777216
    const int n4 = n / 4;               // divisible by 4

    const float4* x    = (const float4*)d_in[0];
    const float4* low  = (const float4*)d_in[1];
    const float4* high = (const float4*)d_in[2];

    float* out = (float*)d_out;
    float4* x_out    = (float4*)(out);
    float4* low_out  = (float4*)(out + (size_t)n);
    float4* high_out = (float4*)(out + 2 * (size_t)n);

    const int block = 256;
    int grid = (n4 + block - 1) / block;
    if (grid > 2048) grid = 2048;       // grid-stride the rest

    abstract_relu_kernel<<<grid, block, 0, stream>>>(x, low, high,
                                                     x_out, low_out, high_out, n4);
}

// Round 2
// 76.258 us; speedup vs baseline: 1.0731x; 1.0731x over previous
//
#include <hip/hip_runtime.h>

// AbstractRelu (DeepPoly ReLU relaxation), elementwise over N=16M fp32.
// Outputs concatenated: [x_out | low_out | high_out], each N floats.
// Memory-bound: 192 MiB in + 192 MiB out, touched once -> nontemporal
// loads/stores to bypass cache allocation. float4 (ext_vector) 16B/lane,
// grid-stride with 2-way unroll for MLP.

#define EPS 1e-7f

typedef float f32x4 __attribute__((ext_vector_type(4)));

__device__ __forceinline__ void relax_one(float X, float L, float H,
                                          float& xo, float& lo, float& ho) {
    xo = fmaxf(X, 0.0f);

    const bool crossing = (L < 0.0f) & (H > 0.0f);
    const bool dead = (H <= 0.0f);

    // Match reference exactly: denom = crossing ? (H-L) : 1.0
    // ub_slope uses denom+EPS, ub_int uses bare denom.
    const float denom = crossing ? (H - L) : 1.0f;
    const float ub_slope = H / (denom + EPS);
    const float ub_int = -(L * H) / denom;
    const float high_cross = ub_slope * H + ub_int;
    // LAMDA = 0 -> low_cross = 0

    ho = crossing ? high_cross : (dead ? 0.0f : H);
    lo = crossing ? 0.0f : (dead ? 0.0f : L);
}

__device__ __forceinline__ void relax_vec(const f32x4& xv, const f32x4& lv,
                                          const f32x4& hv, f32x4& xr,
                                          f32x4& lr, f32x4& hr) {
    float a, b, c;
    relax_one(xv.x, lv.x, hv.x, a, b, c); xr.x = a; lr.x = b; hr.x = c;
    relax_one(xv.y, lv.y, hv.y, a, b, c); xr.y = a; lr.y = b; hr.y = c;
    relax_one(xv.z, lv.z, hv.z, a, b, c); xr.z = a; lr.z = b; hr.z = c;
    relax_one(xv.w, lv.w, hv.w, a, b, c); xr.w = a; lr.w = b; hr.w = c;
}

__global__ void __launch_bounds__(256)
abstract_relu_kernel(const f32x4* __restrict__ x,
                     const f32x4* __restrict__ low,
                     const f32x4* __restrict__ high,
                     f32x4* __restrict__ x_out,
                     f32x4* __restrict__ low_out,
                     f32x4* __restrict__ high_out,
                     int n4) {
    const int stride = gridDim.x * blockDim.x;
    int i = blockIdx.x * blockDim.x + threadIdx.x;

    // 2-way unrolled grid-stride: two independent load groups in flight.
    for (; i + stride < n4; i += 2 * stride) {
        const int j = i + stride;
        const f32x4 xv0 = __builtin_nontemporal_load(&x[i]);
        const f32x4 lv0 = __builtin_nontemporal_load(&low[i]);
        const f32x4 hv0 = __builtin_nontemporal_load(&high[i]);
        const f32x4 xv1 = __builtin_nontemporal_load(&x[j]);
        const f32x4 lv1 = __builtin_nontemporal_load(&low[j]);
        const f32x4 hv1 = __builtin_nontemporal_load(&high[j]);

        f32x4 xr0, lr0, hr0, xr1, lr1, hr1;
        relax_vec(xv0, lv0, hv0, xr0, lr0, hr0);
        relax_vec(xv1, lv1, hv1, xr1, lr1, hr1);

        __builtin_nontemporal_store(xr0, &x_out[i]);
        __builtin_nontemporal_store(lr0, &low_out[i]);
        __builtin_nontemporal_store(hr0, &high_out[i]);
        __builtin_nontemporal_store(xr1, &x_out[j]);
        __builtin_nontemporal_store(lr1, &low_out[j]);
        __builtin_nontemporal_store(hr1, &high_out[j]);
    }
    // tail
    if (i < n4) {
        const f32x4 xv = __builtin_nontemporal_load(&x[i]);
        const f32x4 lv = __builtin_nontemporal_load(&low[i]);
        const f32x4 hv = __builtin_nontemporal_load(&high[i]);
        f32x4 xr, lr, hr;
        relax_vec(xv, lv, hv, xr, lr, hr);
        __builtin_nontemporal_store(xr, &x_out[i]);
        __builtin_nontemporal_store(lr, &low_out[i]);
        __builtin_nontemporal_store(hr, &high_out[i]);
    }
}

extern "C" void kernel_launch(void* const* d_in, const int* in_sizes, int n_in,
                              void* d_out, int out_size, void* d_ws, size_t ws_size,
                              hipStream_t stream) {
    const int n = in_sizes[0];          // 16777216
    const int n4 = n / 4;               // divisible by 4

    const f32x4* x    = (const f32x4*)d_in[0];
    const f32x4* low  = (const f32x4*)d_in[1];
    const f32x4* high = (const f32x4*)d_in[2];

    float* out = (float*)d_out;
    f32x4* x_out    = (f32x4*)(out);
    f32x4* low_out  = (f32x4*)(out + (size_t)n);
    f32x4* high_out = (f32x4*)(out + 2 * (size_t)n);

    const int block = 256;
    int grid = (n4 + block - 1) / block;
    if (grid > 2048) grid = 2048;       // grid-stride the rest

    abstract_relu_kernel<<<grid, block, 0, stream>>>(x, low, high,
                                                     x_out, low_out, high_out, n4);
}